// Round 1
// baseline (452.590 us; speedup 1.0000x reference)
//
#include <hip/hip_runtime.h>
#include <hip/hip_bf16.h>
#include <stdint.h>

// SymbolicDecoder fused MLP evaluation, MI355X gfx950.
// Parts (out = (4096, 22, 2) f32):
//   p 0-2  : net0 on slots {0,1,2}    (rows r = b*3+s,  K=1024)
//   p 3    : net1 on slot 6           (rows r = b,      K=1024)
//   p 4    : net2 on slot 6           (rows r = b,      K=1024)
//   p 5-18 : double net on 14 pairs   (rows r = b*14+k, K=2048)
//   p 19-21: net3 on slots {0,1,2}    (rows r = b*3+s,  K=1024)
// Strategy: bf16 MFMA (16x16x32), f32 accumulate. Weights pre-converted to a
// fragment-ready bf16 layout in d_ws (12.6 MB needed) so B staging is pure
// global_load_lds dwordx4. Epilogue fuses bias+ReLU+w2-reduction, atomicAdd
// into out (out pre-initialized with b2).

typedef __attribute__((ext_vector_type(4))) float f32x4;
typedef __attribute__((ext_vector_type(8))) short short8;
typedef __attribute__((ext_vector_type(8))) __bf16 bf16x8;
typedef __attribute__((ext_vector_type(4))) unsigned short us4;

__device__ inline unsigned short f2bf(float f) {
  union { float f; uint32_t u; } x; x.f = f;
  uint32_t u = x.u;
  return (unsigned short)((u + 0x7fffu + ((u >> 16) & 1u)) >> 16);
}

// ---------------- out init: out[b][p][c] = b2(part(p))[c] ----------------
__global__ void init_out(float* __restrict__ out,
                         const float* __restrict__ sb2,
                         const float* __restrict__ db2) {
  int i = blockIdx.x * 256 + threadIdx.x;
  if (i >= 180224) return;
  int c = i & 1;
  int p = (i >> 1) % 22;
  float v;
  if (p < 3)       v = sb2[0 + c];
  else if (p == 3) v = sb2[2 + c];
  else if (p == 4) v = sb2[4 + c];
  else if (p < 19) v = db2[c];
  else             v = sb2[6 + c];
  out[i] = v;
}

// ---------------- weight prep: f32 -> bf16, fragment-ready layout --------
// Layout per (kstep, coltile) 32KB tile, 16B chunk index:
//   chunk = kk*1024 + nblk*64 + kgrp*16 + j15 ; elems e=0..7 along k
//   k = kstep*64 + kk*32 + kgrp*8 + e ; j = coltile*256 + nblk*16 + j15
// Regions (ushort elems): net n at n*1048576 (16 ksteps), double at 4194304
// (32 ksteps). Total 6291456 ushorts = 12.58 MB in d_ws.
__global__ void prep_weights(const float* __restrict__ sw1,
                             const float* __restrict__ dw1,
                             unsigned short* __restrict__ wp) {
  int c = blockIdx.x * 256 + threadIdx.x;  // 786432 chunks total
  const float* W;
  size_t ob;
  int local;
  if (c < 524288) {
    int net = c >> 17;
    local = c & 131071;
    W = sw1 + (size_t)net * 1048576;
    ob = (size_t)net * 1048576;
  } else {
    local = c - 524288;
    W = dw1;
    ob = 4194304;
  }
  int c2 = local & 2047;
  int tile = local >> 11;
  int ct = tile & 3;
  int kstep = tile >> 2;
  int kk = c2 >> 10, nblk = (c2 >> 6) & 15, kgrp = (c2 >> 4) & 3, j15 = c2 & 15;
  int kb = kstep * 64 + kk * 32 + kgrp * 8;
  int j = ct * 256 + nblk * 16 + j15;
  short8 v;
#pragma unroll
  for (int e = 0; e < 8; e++) v[e] = (short)f2bf(W[(size_t)(kb + e) * 1024 + j]);
  *(short8*)(wp + ob + (size_t)local * 8) = v;
}

// ---------------- fused main ----------------
__global__ __launch_bounds__(256) void fused_main(
    const float* __restrict__ feat, const float* __restrict__ sb1,
    const float* __restrict__ sw2, const float* __restrict__ db1,
    const float* __restrict__ dw2, const unsigned short* __restrict__ wp,
    float* __restrict__ out) {
  __shared__ short8 Abuf[512];    // 8 KB : 64 rows x 64 k, fragment-ready
  __shared__ short8 Bbuf[2048];   // 32 KB: 64 k x 256 j, fragment-ready

  const int tid = threadIdx.x;
  const int lane = tid & 63;
  const int wid = tid >> 6;
  const int bid = blockIdx.x;
  const int ct = bid & 3;       // hidden-col tile (256 cols each)
  const int rt = bid >> 2;      // row tile (64 rows)

  int task, nsteps, rbase;
  const unsigned short* wpt;
  const float* b1;
  const float* w2;
  if (rt < 192)       { task = 0; rbase = rt * 64;          wpt = wp;           b1 = sb1;        w2 = sw2;        nsteps = 16; }
  else if (rt < 256)  { task = 1; rbase = (rt - 192) * 64;  wpt = wp + 1048576; b1 = sb1 + 1024; w2 = sw2 + 2048; nsteps = 16; }
  else if (rt < 320)  { task = 2; rbase = (rt - 256) * 64;  wpt = wp + 2097152; b1 = sb1 + 2048; w2 = sw2 + 4096; nsteps = 16; }
  else if (rt < 1216) { task = 3; rbase = (rt - 320) * 64;  wpt = wp + 4194304; b1 = db1;        w2 = dw2;        nsteps = 32; }
  else                { task = 4; rbase = (rt - 1216) * 64; wpt = wp + 3145728; b1 = sb1 + 3072; w2 = sw2 + 6144; nsteps = 16; }

  // A staging: thread t owns row (t>>2), float4 slots (t&3)+4*rep
  const int arow_l = tid >> 2;
  const int arow = rbase + arow_l;
  int ab, as1, as2;
  if (task == 0 || task == 4) {
    ab = arow / 3; int s = arow - ab * 3; as1 = s; as2 = s;
  } else if (task == 3) {
    ab = arow / 14; int pp = arow - ab * 14;
    if (pp < 12) { as1 = pp >> 2; as2 = 3 + (pp & 3); }
    else         { as1 = 4;       as2 = (pp == 12) ? 5 : 6; }
  } else {
    ab = arow; as1 = 6; as2 = 6;
  }
  const float* aptr1 = feat + ((size_t)ab * 7 + as1) * 1024;
  const float* aptr2 = feat + ((size_t)ab * 7 + as2) * 1024;
  char* abase = (char*)Abuf + (arow_l >> 4) * 1024 + (arow_l & 15) * 16;

  f32x4 acc[4][4] = {};

  for (int ks = 0; ks < nsteps; ks++) {
    // ---- stage A (f32 -> bf16 -> LDS, fragment-ready) ----
    const float* src = (ks < 16) ? (aptr1 + ks * 64) : (aptr2 + (ks - 16) * 64);
#pragma unroll
    for (int rep = 0; rep < 4; rep++) {
      int kl = (tid & 3) * 4 + rep * 16;  // 0..60, 4 consecutive k
      f32x4 v = *(const f32x4*)(src + kl);
      us4 pk;
      pk[0] = f2bf(v[0]); pk[1] = f2bf(v[1]); pk[2] = f2bf(v[2]); pk[3] = f2bf(v[3]);
      *(us4*)(abase + (kl >> 5) * 4096 + ((kl >> 3) & 3) * 256 + (kl & 7) * 2) = pk;
    }
    // ---- stage B (global_load_lds dwordx4 from prepped bf16) ----
    const unsigned short* wsrc = wpt + (size_t)(ks * 4 + ct) * 16384;
#pragma unroll
    for (int i = 0; i < 8; i++) {
      __builtin_amdgcn_global_load_lds(
          (const __attribute__((address_space(1))) void*)(wsrc + i * 2048 + tid * 8),
          (__attribute__((address_space(3))) void*)((char*)Bbuf + i * 4096 + wid * 1024),
          16, 0, 0);
    }
    __syncthreads();
    // ---- MFMA: wave w owns cols [w*64, w*64+64) of the 256-col tile ----
#pragma unroll
    for (int kk = 0; kk < 2; kk++) {
      short8 afr[4], bfr[4];
#pragma unroll
      for (int m = 0; m < 4; m++)
        afr[m] = Abuf[kk * 256 + m * 64 + (lane >> 4) * 16 + (lane & 15)];
#pragma unroll
      for (int n = 0; n < 4; n++)
        bfr[n] = Bbuf[kk * 1024 + (wid * 4 + n) * 64 + (lane >> 4) * 16 + (lane & 15)];
#pragma unroll
      for (int m = 0; m < 4; m++)
#pragma unroll
        for (int n = 0; n < 4; n++)
          acc[m][n] = __builtin_amdgcn_mfma_f32_16x16x32_bf16(
              __builtin_bit_cast(bf16x8, afr[m]),
              __builtin_bit_cast(bf16x8, bfr[n]), acc[m][n], 0, 0, 0);
    }
    __syncthreads();
  }

  // ---- epilogue: h = relu(acc + b1); partial out = h . w2 ; atomicAdd ----
  float b1v[4], w20v[4], w21v[4];
#pragma unroll
  for (int n = 0; n < 4; n++) {
    int j = ct * 256 + wid * 64 + n * 16 + (lane & 15);
    b1v[n] = b1[j];
    w20v[n] = w2[2 * j];
    w21v[n] = w2[2 * j + 1];
  }
#pragma unroll
  for (int m = 0; m < 4; m++) {
#pragma unroll
    for (int r = 0; r < 4; r++) {
      float s0 = 0.f, s1 = 0.f;
#pragma unroll
      for (int n = 0; n < 4; n++) {
        float h = acc[m][n][r] + b1v[n];
        h = fmaxf(h, 0.f);
        s0 = fmaf(h, w20v[n], s0);
        s1 = fmaf(h, w21v[n], s1);
      }
#pragma unroll
      for (int off = 1; off < 16; off <<= 1) {
        s0 += __shfl_xor(s0, off, 64);
        s1 += __shfl_xor(s1, off, 64);
      }
      if ((lane & 15) == 0) {
        int rg = rbase + m * 16 + (lane >> 4) * 4 + r;
        int b, p;
        if (task == 0)      { b = rg / 3;  p = rg - b * 3; }
        else if (task == 1) { b = rg;      p = 3; }
        else if (task == 2) { b = rg;      p = 4; }
        else if (task == 3) { b = rg / 14; p = 5 + (rg - b * 14); }
        else                { b = rg / 3;  p = 19 + (rg - b * 3); }
        atomicAdd(out + ((size_t)b * 44 + p * 2), s0);
        atomicAdd(out + ((size_t)b * 44 + p * 2 + 1), s1);
      }
    }
  }
}

extern "C" void kernel_launch(void* const* d_in, const int* in_sizes, int n_in,
                              void* d_out, int out_size, void* d_ws, size_t ws_size,
                              hipStream_t stream) {
  const float* feat = (const float*)d_in[0];
  const float* sw1  = (const float*)d_in[1];
  const float* sb1  = (const float*)d_in[2];
  const float* sw2  = (const float*)d_in[3];
  const float* sb2  = (const float*)d_in[4];
  const float* dw1  = (const float*)d_in[5];
  const float* db1  = (const float*)d_in[6];
  const float* dw2  = (const float*)d_in[7];
  const float* db2  = (const float*)d_in[8];
  float* out = (float*)d_out;
  unsigned short* wp = (unsigned short*)d_ws;  // needs 12,582,912 bytes

  init_out<<<704, 256, 0, stream>>>(out, sb2, db2);
  prep_weights<<<3072, 256, 0, stream>>>(sw1, dw1, wp);
  // 1408 row-tiles (192 T0 | 64 T1 | 64 T2 | 896 T3 | 192 T4) x 4 col-tiles
  fused_main<<<5632, 256, 0, stream>>>(feat, sb1, sw2, db1, dw2, wp, out);
}